// Round 13
// baseline (363.494 us; speedup 1.0000x reference)
//
#include <hip/hip_runtime.h>
#include <hip/hip_bf16.h>
#include <stdint.h>

typedef __bf16 bf16x8 __attribute__((ext_vector_type(8)));
typedef float  f32x4  __attribute__((ext_vector_type(4)));

static constexpr float kScale = 0.0078125f;  // 1/128

// ---------- f32 -> bf16 (RNE) convert, 8 elems/thread ----------
static __device__ __forceinline__ uint32_t bf16_rne(float f) {
  uint32_t u = __builtin_bit_cast(uint32_t, f);
  u += 0x7FFFu + ((u >> 16) & 1u);
  return u >> 16;
}
static __device__ __forceinline__ uint32_t pack2(float lo, float hi) {
  return bf16_rne(lo) | (bf16_rne(hi) << 16);
}

__global__ __launch_bounds__(256) void cvt_f32_to_bf16(
    const float* __restrict__ src, uint4* __restrict__ dst) {
  const int i = blockIdx.x * 256 + threadIdx.x;
  const float4* sv = reinterpret_cast<const float4*>(src);
  float4 a = sv[2 * i];
  float4 b = sv[2 * i + 1];
  uint4 o;
  o.x = pack2(a.x, a.y);
  o.y = pack2(a.z, a.w);
  o.z = pack2(b.x, b.y);
  o.w = pack2(b.z, b.w);
  dst[i] = o;
}

// ---------- async global->LDS, 16B per lane ----------
static __device__ __forceinline__ void gload_lds16(const void* g, void* l) {
  __builtin_amdgcn_global_load_lds(
      (const __attribute__((address_space(1))) void*)g,
      (__attribute__((address_space(3))) void*)l, 16, 0, 0);
}

#define BARRIER() __builtin_amdgcn_s_barrier()
#define VMW(n) asm volatile("s_waitcnt vmcnt(" #n ")" ::: "memory")

// =====================================================================
// R13 = R12 phase structure (one barrier per phase AFTER the MFMA
// cluster; vmcnt(6) only at P4/P8; 8bm x 4bn super-tile; setprio) with
// the MFMA shape reverted to 16x16x32 (m201's choice): per phase 16
// MFMA = 8 independent acc chains of depth 2 (vs 32x32's 2 chains of
// depth 4) -> dep-latency hiding within the MFMA window.  Read shape
// and staging swizzle are R4's (measured 0 bank conflicts).
// =====================================================================
constexpr int TILE_V = (256 * 64) / 8;  // bf16x8 vectors per buffer

template <int MH, int NH>
__device__ __forceinline__ void quad16(f32x4 (&acc)[8][4],
                                       const bf16x8 (&aF)[4][2],
                                       const bf16x8 (&bF)[2][2]) {
  __builtin_amdgcn_s_setprio(1);
#pragma unroll
  for (int kk = 0; kk < 2; ++kk)
#pragma unroll
    for (int mi = 0; mi < 4; ++mi)
#pragma unroll
      for (int ni = 0; ni < 2; ++ni)
        acc[MH * 4 + mi][NH * 2 + ni] = __builtin_amdgcn_mfma_f32_16x16x32_bf16(
            aF[mi][kk], bF[ni][kk], acc[MH * 4 + mi][NH * 2 + ni], 0, 0, 0);
  __builtin_amdgcn_s_setprio(0);
}

// R4's proven conflict-free addressing: ac0 = fh ^ (fr&7); kk -> ac0^4.
template <int BUF, int MH>
__device__ __forceinline__ void loadA16(bf16x8 (&aF)[4][2], const bf16x8* Av,
                                        int wr, int fr, int ac0) {
#pragma unroll
  for (int mi = 0; mi < 4; ++mi) {
    const int row = (MH << 7) + (wr << 6) + (mi << 4) + fr;
    aF[mi][0] = Av[BUF * TILE_V + row * 8 + ac0];
    aF[mi][1] = Av[BUF * TILE_V + row * 8 + (ac0 ^ 4)];
  }
}
template <int BUF, int NH>
__device__ __forceinline__ void loadB16(bf16x8 (&bF)[2][2], const bf16x8* Bv,
                                        int wc, int fr, int ac0) {
#pragma unroll
  for (int ni = 0; ni < 2; ++ni) {
    const int row = (NH << 7) + (wc << 5) + (ni << 4) + fr;
    bF[ni][0] = Bv[BUF * TILE_V + row * 8 + ac0];
    bF[ni][1] = Bv[BUF * TILE_V + row * 8 + (ac0 ^ 4)];
  }
}

__global__ __launch_bounds__(512, 2) void gemm256_8phase(
    const uint16_t* __restrict__ A, const uint16_t* __restrict__ B,
    const float* __restrict__ bias, float* __restrict__ C,
    int Mi, int Ni, int Ki) {
  __shared__ __align__(16) uint16_t As[2][256 * 64];  // 64 KB
  __shared__ __align__(16) uint16_t Bs[2][256 * 64];  // 64 KB

  const int tid = threadIdx.x;
  const int l   = tid & 63;
  const int wv  = tid >> 6;
  const int wr  = wv >> 2;   // 0..1
  const int wc  = wv & 3;    // 0..3
  const int fr  = l & 15;
  const int fh  = l >> 4;
  const int l8  = l >> 3;
  const int l7  = l & 7;

  const int ac0 = fh ^ (fr & 7);

  const int nbm = Mi >> 8, nbn = Ni >> 8;
  const int nwg = nbm * nbn;
  const int q = nwg >> 3, r = nwg & 7;
  const int xcd = (int)blockIdx.x & 7, orig = (int)blockIdx.x >> 3;
  const int swz = (xcd < r ? xcd * (q + 1) : r * (q + 1) + (xcd - r) * q) + orig;

  // 8bm x 4bn super-tile mapping (L2 dedup across concurrent CUs)
  int bm, bn;
  if ((nbm & 7) == 0 && (nbn & 3) == 0) {
    const int s = swz >> 5;
    const int o = swz & 31;
    const int nsc = nbn >> 2;
    bm = (s / nsc) * 8 + (o >> 2);
    bn = (s % nsc) * 4 + (o & 3);
  } else {
    bm = swz / nbn;
    bn = swz % nbn;
  }

  // staging: wave wv covers rows chunk+wv*8+l8; global col inverse-swizzled
  const int xcol = (l7 ^ l8) << 3;
  const uint16_t* gA0 = A + (size_t)((bm << 8) + (wv << 3) + l8) * Ki + xcol;
  const uint16_t* gB0 = B + (size_t)((bn << 8) + (wv << 3) + l8) * Ki + xcol;

#define STAGE_A(bufi, chunk, t)                        \
  gload_lds16(gA0 + (size_t)(chunk) * Ki + (t) * 64,   \
              &As[bufi][((chunk) + (wv << 3)) << 6])
#define STAGE_B(bufi, chunk, t)                        \
  gload_lds16(gB0 + (size_t)(chunk) * Ki + (t) * 64,   \
              &Bs[bufi][((chunk) + (wv << 3)) << 6])

  const bf16x8* Av = reinterpret_cast<const bf16x8*>(&As[0][0]);
  const bf16x8* Bv = reinterpret_cast<const bf16x8*>(&Bs[0][0]);

  f32x4 acc[8][4] = {};
  bf16x8 aF[4][2], b0[2][2], b1[2][2];

  const int NT = Ki >> 6;   // K-tiles (Ki % 128 == 0, Ki >= 256)
  const int NI = NT >> 1;

  // ---- prologue: t0 all 4 halves + t1 {Ah0,Bh0,Bh1} ----
  STAGE_A(0, 0, 0);   STAGE_A(0, 64, 0);    // t0 A-h0
  STAGE_B(0, 0, 0);   STAGE_B(0, 64, 0);    // t0 B-h0
  STAGE_B(0, 128, 0); STAGE_B(0, 192, 0);   // t0 B-h1
  STAGE_A(0, 128, 0); STAGE_A(0, 192, 0);   // t0 A-h1
  STAGE_A(1, 0, 1);   STAGE_A(1, 64, 1);    // t1 A-h0
  STAGE_B(1, 0, 1);   STAGE_B(1, 64, 1);    // t1 B-h0
  STAGE_B(1, 128, 1); STAGE_B(1, 192, 1);   // t1 B-h1
  VMW(6);
  BARRIER();

#pragma unroll 1
  for (int i = 0; i < NI - 1; ++i) {
    const int t1 = 2 * i + 1, t2 = 2 * i + 2, t3 = 2 * i + 3;

    // P1: reads buf0 {Bh0, Ah0} ; stage t1 A-h1 ; Q(0,0) ; BAR
    loadB16<0, 0>(b0, Bv, wc, fr, ac0);
    loadA16<0, 0>(aF, Av, wr, fr, ac0);
    STAGE_A(1, 128, t1); STAGE_A(1, 192, t1);
    quad16<0, 0>(acc, aF, b0);
    BARRIER();

    // P2: reads buf0 Bh1 ; stage t2 A-h0 ; Q(0,1) ; BAR
    loadB16<0, 1>(b1, Bv, wc, fr, ac0);
    STAGE_A(0, 0, t2); STAGE_A(0, 64, t2);
    quad16<0, 1>(acc, aF, b1);
    BARRIER();

    // P3: reads buf0 Ah1 ; stage t2 B-h0 ; Q(1,0) ; BAR
    loadA16<0, 1>(aF, Av, wr, fr, ac0);
    STAGE_B(0, 0, t2); STAGE_B(0, 64, t2);
    quad16<1, 0>(acc, aF, b0);
    BARRIER();

    // P4: stage t2 B-h1 ; Q(1,1) ; VMW(6) forces all of t1 ; BAR
    STAGE_B(0, 128, t2); STAGE_B(0, 192, t2);
    quad16<1, 1>(acc, aF, b1);
    VMW(6);
    BARRIER();

    // P5: reads buf1 {Bh0, Ah0} ; stage t2 A-h1 ; Q(0,0) ; BAR
    loadB16<1, 0>(b0, Bv, wc, fr, ac0);
    loadA16<1, 0>(aF, Av, wr, fr, ac0);
    STAGE_A(0, 128, t2); STAGE_A(0, 192, t2);
    quad16<0, 0>(acc, aF, b0);
    BARRIER();

    // P6: reads buf1 Bh1 ; stage t3 A-h0 ; Q(0,1) ; BAR
    loadB16<1, 1>(b1, Bv, wc, fr, ac0);
    STAGE_A(1, 0, t3); STAGE_A(1, 64, t3);
    quad16<0, 1>(acc, aF, b1);
    BARRIER();

    // P7: reads buf1 Ah1 ; stage t3 B-h0 ; Q(1,0) ; BAR
    loadA16<1, 1>(aF, Av, wr, fr, ac0);
    STAGE_B(1, 0, t3); STAGE_B(1, 64, t3);
    quad16<1, 0>(acc, aF, b0);
    BARRIER();

    // P8: stage t3 B-h1 ; Q(1,1) ; VMW(6) forces all of t2 ; BAR
    STAGE_B(1, 128, t3); STAGE_B(1, 192, t3);
    quad16<1, 1>(acc, aF, b1);
    VMW(6);
    BARRIER();
  }

  // ---- peeled last iteration (tiles NT-2 buf0, NT-1 buf1) ----
  {
    const int t1 = NT - 1;
    // P1
    loadB16<0, 0>(b0, Bv, wc, fr, ac0);
    loadA16<0, 0>(aF, Av, wr, fr, ac0);
    STAGE_A(1, 128, t1); STAGE_A(1, 192, t1);
    quad16<0, 0>(acc, aF, b0);
    BARRIER();
    // P2
    loadB16<0, 1>(b1, Bv, wc, fr, ac0);
    quad16<0, 1>(acc, aF, b1);
    BARRIER();
    // P3
    loadA16<0, 1>(aF, Av, wr, fr, ac0);
    quad16<1, 0>(acc, aF, b0);
    BARRIER();
    // P4: drain everything so buf1 (t_{NT-1}) is complete
    quad16<1, 1>(acc, aF, b1);
    VMW(0);
    BARRIER();
    // P5
    loadB16<1, 0>(b0, Bv, wc, fr, ac0);
    loadA16<1, 0>(aF, Av, wr, fr, ac0);
    quad16<0, 0>(acc, aF, b0);
    BARRIER();
    // P6
    loadB16<1, 1>(b1, Bv, wc, fr, ac0);
    quad16<0, 1>(acc, aF, b1);
    BARRIER();
    // P7
    loadA16<1, 1>(aF, Av, wr, fr, ac0);
    quad16<1, 0>(acc, aF, b0);
    BARRIER();
    // P8 (register-only)
    quad16<1, 1>(acc, aF, b1);
  }

  // ---- epilogue (16x16 C/D layout, m89/m91): col = fr, row = fh*4+j;
  // rows = mh*128+wr*64+mi*16+fh*4+j ; cols = nh*128+wc*32+ni*16+fr
  const int rowB = (bm << 8) + (wr << 6);
  const int colB = (bn << 8) + (wc << 5);
#pragma unroll
  for (int n = 0; n < 4; ++n) {
    const int col = colB + (n >> 1) * 128 + (n & 1) * 16 + fr;
    const float bv = bias[col];
#pragma unroll
    for (int m = 0; m < 8; ++m) {
      const int row = rowB + (m >> 2) * 128 + (m & 3) * 16 + fh * 4;
#pragma unroll
      for (int j = 0; j < 4; ++j)
        C[(size_t)(row + j) * Ni + col] = acc[m][n][j] * kScale + bv;
    }
  }
}

// =====================================================================
// proven 128x128 fallback for non-conforming shapes
// =====================================================================
__global__ __launch_bounds__(256) void gemm_bf16_bias(
    const uint16_t* __restrict__ A, const uint16_t* __restrict__ B,
    const float* __restrict__ bias, float* __restrict__ C,
    int Mi, int Ni, int Ki) {
  __shared__ __align__(16) uint16_t As[128 * 32];
  __shared__ __align__(16) uint16_t Bs[128 * 32];

  const int tid  = threadIdx.x;
  const int lane = tid & 63;
  const int wv   = tid >> 6;
  const int wr   = wv >> 1;
  const int wc   = wv & 1;
  const int fr   = lane & 15;
  const int fh   = lane >> 4;

  const int nTilesN = Ni >> 7;
  const int nwg = gridDim.x;
  const int q = nwg >> 3, r = nwg & 7;
  const int xcd = (int)blockIdx.x & 7, orig = (int)blockIdx.x >> 3;
  const int swz = (xcd < r ? xcd * (q + 1) : r * (q + 1) + (xcd - r) * q) + orig;
  const int bm = swz / nTilesN;
  const int bn = swz % nTilesN;

  const int sRow = tid >> 2;
  const int sCol = (tid & 3) << 3;

  const uint16_t* gA0 = A + (size_t)(bm * 128 + sRow) * Ki + sCol;
  const uint16_t* gA1 = gA0 + (size_t)64 * Ki;
  const uint16_t* gB0 = B + (size_t)(bn * 128 + sRow) * Ki + sCol;
  const uint16_t* gB1 = gB0 + (size_t)64 * Ki;
  uint16_t* lA0 = &As[tid * 8];
  uint16_t* lA1 = &As[(256 + tid) * 8];
  uint16_t* lB0 = &Bs[tid * 8];
  uint16_t* lB1 = &Bs[(256 + tid) * 8];

  const bf16x8* Av = reinterpret_cast<const bf16x8*>(As);
  const bf16x8* Bv = reinterpret_cast<const bf16x8*>(Bs);

  f32x4 acc[4][4] = {};

  for (int k0 = 0; k0 < Ki; k0 += 32) {
    gload_lds16(gA0 + k0, lA0);
    gload_lds16(gA1 + k0, lA1);
    gload_lds16(gB0 + k0, lB0);
    gload_lds16(gB1 + k0, lB1);
    __syncthreads();

    bf16x8 af[4], bfr[4];
#pragma unroll
    for (int m = 0; m < 4; ++m) af[m] = Av[(wr * 64 + m * 16 + fr) * 4 + fh];
#pragma unroll
    for (int n = 0; n < 4; ++n) bfr[n] = Bv[(wc * 64 + n * 16 + fr) * 4 + fh];

#pragma unroll
    for (int m = 0; m < 4; ++m)
#pragma unroll
      for (int n = 0; n < 4; ++n)
        acc[m][n] = __builtin_amdgcn_mfma_f32_16x16x32_bf16(af[m], bfr[n],
                                                            acc[m][n], 0, 0, 0);
    __syncthreads();
  }

  const int rowBase = bm * 128 + wr * 64;
  const int colBase = bn * 128 + wc * 64;
#pragma unroll
  for (int n = 0; n < 4; ++n) {
    const int col = colBase + n * 16 + fr;
    const float bv = bias[col];
#pragma unroll
    for (int m = 0; m < 4; ++m) {
      const int row = rowBase + m * 16 + fh * 4;
#pragma unroll
      for (int j = 0; j < 4; ++j)
        C[(size_t)(row + j) * Ni + col] = acc[m][n][j] * kScale + bv;
    }
  }
}

// ---------- fallback: naive f32 ----------
__global__ void naive_gemm(const float* __restrict__ x, const float* __restrict__ w,
                           const float* __restrict__ bias, float* __restrict__ out,
                           int Mi, int Ni, int Ki) {
  long idx = (long)blockIdx.x * blockDim.x + threadIdx.x;
  if (idx >= (long)Mi * Ni) return;
  int m = (int)(idx / Ni), n = (int)(idx % Ni);
  float s = 0.f;
  for (int k = 0; k < Ki; ++k) s += x[(long)m * Ki + k] * w[(long)n * Ki + k];
  out[idx] = s * kScale + bias[n];
}

extern "C" void kernel_launch(void* const* d_in, const int* in_sizes, int n_in,
                              void* d_out, int out_size, void* d_ws, size_t ws_size,
                              hipStream_t stream) {
  const float* x    = (const float*)d_in[0];
  const float* w    = (const float*)d_in[1];
  const float* bias = (const float*)d_in[2];
  float* out = (float*)d_out;

  const int Ni = in_sizes[2];
  const int Ki = in_sizes[1] / Ni;
  const int Mi = in_sizes[0] / Ki;

  const size_t nx = (size_t)Mi * Ki;
  const size_t nw = (size_t)Ni * Ki;

  if (ws_size >= (nx + nw) * sizeof(uint16_t) && (Ki % 32) == 0 &&
      (Mi % 128) == 0 && (Ni % 128) == 0) {
    uint16_t* xb = (uint16_t*)d_ws;
    uint16_t* wb = xb + nx;
    cvt_f32_to_bf16<<<(int)(nx / 2048), 256, 0, stream>>>(x, (uint4*)xb);
    cvt_f32_to_bf16<<<(int)(nw / 2048), 256, 0, stream>>>(w, (uint4*)wb);

    if ((Mi % 256) == 0 && (Ni % 256) == 0 && (Ki % 128) == 0 && Ki >= 256) {
      dim3 grid((Mi / 256) * (Ni / 256));
      gemm256_8phase<<<grid, 512, 0, stream>>>(xb, wb, bias, out, Mi, Ni, Ki);
    } else {
      dim3 grid((Mi / 128) * (Ni / 128));
      gemm_bf16_bias<<<grid, 256, 0, stream>>>(xb, wb, bias, out, Mi, Ni, Ki);
    }
  } else {
    long total = (long)Mi * Ni;
    naive_gemm<<<(int)((total + 255) / 256), 256, 0, stream>>>(x, w, bias, out,
                                                               Mi, Ni, Ki);
  }
}

// Round 14
// 338.643 us; speedup vs baseline: 1.0734x; 1.0734x over previous
//
#include <hip/hip_runtime.h>
#include <hip/hip_bf16.h>
#include <stdint.h>

typedef __bf16 bf16x8 __attribute__((ext_vector_type(8)));
typedef float  f32x4  __attribute__((ext_vector_type(4)));
typedef float  f32x16 __attribute__((ext_vector_type(16)));

static constexpr float kScale = 0.0078125f;  // 1/128

// ---------- f32 -> bf16 (RNE) convert, 8 elems/thread ----------
static __device__ __forceinline__ uint32_t bf16_rne(float f) {
  uint32_t u = __builtin_bit_cast(uint32_t, f);
  u += 0x7FFFu + ((u >> 16) & 1u);
  return u >> 16;
}
static __device__ __forceinline__ uint32_t pack2(float lo, float hi) {
  return bf16_rne(lo) | (bf16_rne(hi) << 16);
}

__global__ __launch_bounds__(256) void cvt_f32_to_bf16(
    const float* __restrict__ src, uint4* __restrict__ dst) {
  const int i = blockIdx.x * 256 + threadIdx.x;
  const float4* sv = reinterpret_cast<const float4*>(src);
  float4 a = sv[2 * i];
  float4 b = sv[2 * i + 1];
  uint4 o;
  o.x = pack2(a.x, a.y);
  o.y = pack2(a.z, a.w);
  o.z = pack2(b.x, b.y);
  o.w = pack2(b.z, b.w);
  dst[i] = o;
}

// ---------- async global->LDS, 16B per lane ----------
static __device__ __forceinline__ void gload_lds16(const void* g, void* l) {
  __builtin_amdgcn_global_load_lds(
      (const __attribute__((address_space(1))) void*)g,
      (__attribute__((address_space(3))) void*)l, 16, 0, 0);
}

#define BARRIER() __builtin_amdgcn_s_barrier()
#define VMW(n) asm volatile("s_waitcnt vmcnt(" #n ")" ::: "memory")

// =====================================================================
// R14 = R12 (stride-8-aware swizzle, 0 conflicts; barrier after MFMA;
// vmcnt(6)@P4/P8; super-tile) + GRAY-CODE QUADRANT ORDER with
// phase-ahead B reads:  Q(0,0) -> Q(0,1) -> Q(1,1) -> Q(1,0).
//   P1: loadA(mh0)+loadB(b1, ahead) + MFMA Q(0,0) [b0 held]
//   P2: no reads                    + MFMA Q(0,1) [aF+b1 held]
//   P3: loadA(mh1)                  + MFMA Q(1,1) [b1 held]
//   P4: no reads; after VMW load b0 for NEXT tile + MFMA Q(1,0) [held]
// -> 4 of 8 phases have zero LDS-read wait (pure MFMA); reads move
// from 12/4/8/0 to 12/0/8/4.  No new register banks (256-reg wall:
// 2048/SIMD / 8 waves = 256/wave; acc 128 + 128 VGPR is exact).
// Stage lines and vmcnt ledger identical to R12 (re-verified).
// =====================================================================
constexpr int TILE_V = (256 * 64) / 8;  // bf16x8 vectors per buffer

template <int MH, int NH>
__device__ __forceinline__ void quad32(f32x16 (&acc)[4][2],
                                       const bf16x8 (&aF)[2][4],
                                       const bf16x8 (&bF)[4]) {
  __builtin_amdgcn_s_setprio(1);
#pragma unroll
  for (int ks = 0; ks < 4; ++ks)
#pragma unroll
    for (int mt = 0; mt < 2; ++mt)
      acc[MH * 2 + mt][NH] = __builtin_amdgcn_mfma_f32_32x32x16_bf16(
          aF[mt][ks], bF[ks], acc[MH * 2 + mt][NH], 0, 0, 0);
  __builtin_amdgcn_s_setprio(0);
}

// vec col for k-slot ks: (ks<<1) ^ erk (stride-8-aware involution, R12).
template <int BUF, int MH>
__device__ __forceinline__ void loadA32(bf16x8 (&aF)[2][4], const bf16x8* Av,
                                        int wr, int l31, int erk) {
#pragma unroll
  for (int ks = 0; ks < 4; ++ks)
#pragma unroll
    for (int mt = 0; mt < 2; ++mt) {
      const int row = (MH << 7) + (wr << 6) + (mt << 5) + l31;
      aF[mt][ks] = Av[BUF * TILE_V + row * 8 + ((ks << 1) ^ erk)];
    }
}
template <int BUF, int NH>
__device__ __forceinline__ void loadB32(bf16x8 (&bF)[4], const bf16x8* Bv,
                                        int wc, int l31, int erk) {
  const int row = (NH << 7) + (wc << 5) + l31;
#pragma unroll
  for (int ks = 0; ks < 4; ++ks)
    bF[ks] = Bv[BUF * TILE_V + row * 8 + ((ks << 1) ^ erk)];
}

__global__ __launch_bounds__(512, 2) void gemm256_8phase(
    const uint16_t* __restrict__ A, const uint16_t* __restrict__ B,
    const float* __restrict__ bias, float* __restrict__ C,
    int Mi, int Ni, int Ki) {
  __shared__ __align__(16) uint16_t As[2][256 * 64];  // 64 KB
  __shared__ __align__(16) uint16_t Bs[2][256 * 64];  // 64 KB

  const int tid = threadIdx.x;
  const int l   = tid & 63;
  const int wv  = tid >> 6;
  const int wr  = wv >> 2;   // 0..1
  const int wc  = wv & 3;    // 0..3
  const int l31 = l & 31;
  const int lk  = l >> 5;
  const int l8  = l >> 3;
  const int l7  = l & 7;

  // read-side granule key (R12)
  const int erk = l7 ^ ((l31 >> 3) & 3) ^ lk ^ (lk << 2);

  const int nbm = Mi >> 8, nbn = Ni >> 8;
  const int nwg = nbm * nbn;
  const int q = nwg >> 3, r = nwg & 7;
  const int xcd = (int)blockIdx.x & 7, orig = (int)blockIdx.x >> 3;
  const int swz = (xcd < r ? xcd * (q + 1) : r * (q + 1) + (xcd - r) * q) + orig;

  // 8bm x 4bn super-tile mapping (L2 dedup across concurrent CUs)
  int bm, bn;
  if ((nbm & 7) == 0 && (nbn & 3) == 0) {
    const int s = swz >> 5;
    const int o = swz & 31;
    const int nsc = nbn >> 2;
    bm = (s / nsc) * 8 + (o >> 2);
    bn = (s % nsc) * 4 + (o & 3);
  } else {
    bm = swz / nbn;
    bn = swz % nbn;
  }

  // staging: inverse-swizzled global source col (R12)
  const int u0   = l7 ^ l8 ^ (wv & 3);
  const int xcol = (u0 ^ ((u0 & 1) << 2)) << 3;
  const uint16_t* gA0 = A + (size_t)((bm << 8) + (wv << 3) + l8) * Ki + xcol;
  const uint16_t* gB0 = B + (size_t)((bn << 8) + (wv << 3) + l8) * Ki + xcol;

#define STAGE_A(bufi, chunk, t)                        \
  gload_lds16(gA0 + (size_t)(chunk) * Ki + (t) * 64,   \
              &As[bufi][((chunk) + (wv << 3)) << 6])
#define STAGE_B(bufi, chunk, t)                        \
  gload_lds16(gB0 + (size_t)(chunk) * Ki + (t) * 64,   \
              &Bs[bufi][((chunk) + (wv << 3)) << 6])

  const bf16x8* Av = reinterpret_cast<const bf16x8*>(&As[0][0]);
  const bf16x8* Bv = reinterpret_cast<const bf16x8*>(&Bs[0][0]);

  f32x16 acc[4][2] = {};
  bf16x8 aF[2][4], b0[4], b1[4];

  const int NT = Ki >> 6;   // K-tiles (Ki % 128 == 0, Ki >= 256)
  const int NI = NT >> 1;

  // ---- prologue: t0 all 4 halves + t1 {Ah0,Bh0,Bh1}; preload b0 ----
  STAGE_A(0, 0, 0);   STAGE_A(0, 64, 0);    // t0 A-h0
  STAGE_B(0, 0, 0);   STAGE_B(0, 64, 0);    // t0 B-h0
  STAGE_B(0, 128, 0); STAGE_B(0, 192, 0);   // t0 B-h1
  STAGE_A(0, 128, 0); STAGE_A(0, 192, 0);   // t0 A-h1
  STAGE_A(1, 0, 1);   STAGE_A(1, 64, 1);    // t1 A-h0
  STAGE_B(1, 0, 1);   STAGE_B(1, 64, 1);    // t1 B-h0
  STAGE_B(1, 128, 1); STAGE_B(1, 192, 1);   // t1 B-h1
  VMW(6);
  BARRIER();
  loadB32<0, 0>(b0, Bv, wc, l31, erk);      // buf0 nh0 (tile 0)

#pragma unroll 1
  for (int i = 0; i < NI - 1; ++i) {
    const int t1 = 2 * i + 1, t2 = 2 * i + 2, t3 = 2 * i + 3;

    // P1: loadA(mh0) + loadB(b1 ahead) ; stage t1 A-h1 ; Q(0,0)[b0 held]
    loadA32<0, 0>(aF, Av, wr, l31, erk);
    loadB32<0, 1>(b1, Bv, wc, l31, erk);
    STAGE_A(1, 128, t1); STAGE_A(1, 192, t1);
    quad32<0, 0>(acc, aF, b0);
    BARRIER();

    // P2: no reads ; stage t2 A-h0 ; Q(0,1)[aF+b1 held]
    STAGE_A(0, 0, t2); STAGE_A(0, 64, t2);
    quad32<0, 1>(acc, aF, b1);
    BARRIER();

    // P3: loadA(mh1) ; stage t2 B-h0 ; Q(1,1)[b1 held]
    loadA32<0, 1>(aF, Av, wr, l31, erk);
    STAGE_B(0, 0, t2); STAGE_B(0, 64, t2);
    quad32<1, 1>(acc, aF, b1);
    BARRIER();

    // P4: Q(1,0)[aF+b0 held] ; stage t2 B-h1 ; VMW ; load b0 (buf1)
    STAGE_B(0, 128, t2); STAGE_B(0, 192, t2);
    quad32<1, 0>(acc, aF, b0);
    VMW(6);
    loadB32<1, 0>(b0, Bv, wc, l31, erk);   // buf1 complete after VMW
    BARRIER();

    // P5: loadA(mh0,buf1) + loadB(b1 ahead) ; stage t2 A-h1 ; Q(0,0)
    loadA32<1, 0>(aF, Av, wr, l31, erk);
    loadB32<1, 1>(b1, Bv, wc, l31, erk);
    STAGE_A(0, 128, t2); STAGE_A(0, 192, t2);
    quad32<0, 0>(acc, aF, b0);
    BARRIER();

    // P6: no reads ; stage t3 A-h0 ; Q(0,1)
    STAGE_A(1, 0, t3); STAGE_A(1, 64, t3);
    quad32<0, 1>(acc, aF, b1);
    BARRIER();

    // P7: loadA(mh1,buf1) ; stage t3 B-h0 ; Q(1,1)
    loadA32<1, 1>(aF, Av, wr, l31, erk);
    STAGE_B(1, 0, t3); STAGE_B(1, 64, t3);
    quad32<1, 1>(acc, aF, b1);
    BARRIER();

    // P8: Q(1,0) ; stage t3 B-h1 ; VMW ; load b0 (buf0, tile t2)
    STAGE_B(1, 128, t3); STAGE_B(1, 192, t3);
    quad32<1, 0>(acc, aF, b0);
    VMW(6);
    loadB32<0, 0>(b0, Bv, wc, l31, erk);   // buf0=t2 complete after VMW
    BARRIER();
  }

  // ---- peeled last iteration (tiles NT-2 buf0, NT-1 buf1) ----
  {
    const int t1 = NT - 1;
    // P1
    loadA32<0, 0>(aF, Av, wr, l31, erk);
    loadB32<0, 1>(b1, Bv, wc, l31, erk);
    STAGE_A(1, 128, t1); STAGE_A(1, 192, t1);
    quad32<0, 0>(acc, aF, b0);
    BARRIER();
    // P2
    quad32<0, 1>(acc, aF, b1);
    BARRIER();
    // P3
    loadA32<0, 1>(aF, Av, wr, l31, erk);
    quad32<1, 1>(acc, aF, b1);
    BARRIER();
    // P4: drain everything so buf1 (t_{NT-1}) is complete, then b0
    quad32<1, 0>(acc, aF, b0);
    VMW(0);
    loadB32<1, 0>(b0, Bv, wc, l31, erk);
    BARRIER();
    // P5
    loadA32<1, 0>(aF, Av, wr, l31, erk);
    loadB32<1, 1>(b1, Bv, wc, l31, erk);
    quad32<0, 0>(acc, aF, b0);
    BARRIER();
    // P6
    quad32<0, 1>(acc, aF, b1);
    BARRIER();
    // P7
    loadA32<1, 1>(aF, Av, wr, l31, erk);
    quad32<1, 1>(acc, aF, b1);
    BARRIER();
    // P8 (register-only)
    quad32<1, 0>(acc, aF, b0);
  }

  // ---- epilogue (32x32 C/D layout, m74/m101): col = lane&31,
  // row = (reg&3) + 8*(reg>>2) + 4*lk within each 32x32 tile.
  const int rowB = (bm << 8) + (wr << 6) + 4 * lk;
  const int colB = (bn << 8) + (wc << 5) + l31;
#pragma unroll
  for (int mt4 = 0; mt4 < 4; ++mt4) {
    const int rBase = rowB + (mt4 >> 1) * 128 + (mt4 & 1) * 32;
#pragma unroll
    for (int nh = 0; nh < 2; ++nh) {
      const int col = colB + nh * 128;
      const float bv = bias[col];
#pragma unroll
      for (int reg = 0; reg < 16; ++reg) {
        const int row = rBase + (reg & 3) + 8 * (reg >> 2);
        C[(size_t)row * Ni + col] = acc[mt4][nh][reg] * kScale + bv;
      }
    }
  }
}

// =====================================================================
// proven 128x128 fallback for non-conforming shapes
// =====================================================================
__global__ __launch_bounds__(256) void gemm_bf16_bias(
    const uint16_t* __restrict__ A, const uint16_t* __restrict__ B,
    const float* __restrict__ bias, float* __restrict__ C,
    int Mi, int Ni, int Ki) {
  __shared__ __align__(16) uint16_t As[128 * 32];
  __shared__ __align__(16) uint16_t Bs[128 * 32];

  const int tid  = threadIdx.x;
  const int lane = tid & 63;
  const int wv   = tid >> 6;
  const int wr   = wv >> 1;
  const int wc   = wv & 1;
  const int fr   = lane & 15;
  const int fh   = lane >> 4;

  const int nTilesN = Ni >> 7;
  const int nwg = gridDim.x;
  const int q = nwg >> 3, r = nwg & 7;
  const int xcd = (int)blockIdx.x & 7, orig = (int)blockIdx.x >> 3;
  const int swz = (xcd < r ? xcd * (q + 1) : r * (q + 1) + (xcd - r) * q) + orig;
  const int bm = swz / nTilesN;
  const int bn = swz % nTilesN;

  const int sRow = tid >> 2;
  const int sCol = (tid & 3) << 3;

  const uint16_t* gA0 = A + (size_t)(bm * 128 + sRow) * Ki + sCol;
  const uint16_t* gA1 = gA0 + (size_t)64 * Ki;
  const uint16_t* gB0 = B + (size_t)(bn * 128 + sRow) * Ki + sCol;
  const uint16_t* gB1 = gB0 + (size_t)64 * Ki;
  uint16_t* lA0 = &As[tid * 8];
  uint16_t* lA1 = &As[(256 + tid) * 8];
  uint16_t* lB0 = &Bs[tid * 8];
  uint16_t* lB1 = &Bs[(256 + tid) * 8];

  const bf16x8* Av = reinterpret_cast<const bf16x8*>(As);
  const bf16x8* Bv = reinterpret_cast<const bf16x8*>(Bs);

  f32x4 acc[4][4] = {};

  for (int k0 = 0; k0 < Ki; k0 += 32) {
    gload_lds16(gA0 + k0, lA0);
    gload_lds16(gA1 + k0, lA1);
    gload_lds16(gB0 + k0, lB0);
    gload_lds16(gB1 + k0, lB1);
    __syncthreads();

    bf16x8 af[4], bfr[4];
#pragma unroll
    for (int m = 0; m < 4; ++m) af[m] = Av[(wr * 64 + m * 16 + fr) * 4 + fh];
#pragma unroll
    for (int n = 0; n < 4; ++n) bfr[n] = Bv[(wc * 64 + n * 16 + fr) * 4 + fh];

#pragma unroll
    for (int m = 0; m < 4; ++m)
#pragma unroll
      for (int n = 0; n < 4; ++n)
        acc[m][n] = __builtin_amdgcn_mfma_f32_16x16x32_bf16(af[m], bfr[n],
                                                            acc[m][n], 0, 0, 0);
    __syncthreads();
  }

  const int rowBase = bm * 128 + wr * 64;
  const int colBase = bn * 128 + wc * 64;
#pragma unroll
  for (int n = 0; n < 4; ++n) {
    const int col = colBase + n * 16 + fr;
    const float bv = bias[col];
#pragma unroll
    for (int m = 0; m < 4; ++m) {
      const int row = rowBase + m * 16 + fh * 4;
#pragma unroll
      for (int j = 0; j < 4; ++j)
        C[(size_t)(row + j) * Ni + col] = acc[m][n][j] * kScale + bv;
    }
  }
}

// ---------- fallback: naive f32 ----------
__global__ void naive_gemm(const float* __restrict__ x, const float* __restrict__ w,
                           const float* __restrict__ bias, float* __restrict__ out,
                           int Mi, int Ni, int Ki) {
  long idx = (long)blockIdx.x * blockDim.x + threadIdx.x;
  if (idx >= (long)Mi * Ni) return;
  int m = (int)(idx / Ni), n = (int)(idx % Ni);
  float s = 0.f;
  for (int k = 0; k < Ki; ++k) s += x[(long)m * Ki + k] * w[(long)n * Ki + k];
  out[idx] = s * kScale + bias[n];
}

extern "C" void kernel_launch(void* const* d_in, const int* in_sizes, int n_in,
                              void* d_out, int out_size, void* d_ws, size_t ws_size,
                              hipStream_t stream) {
  const float* x    = (const float*)d_in[0];
  const float* w    = (const float*)d_in[1];
  const float* bias = (const float*)d_in[2];
  float* out = (float*)d_out;

  const int Ni = in_sizes[2];
  const int Ki = in_sizes[1] / Ni;
  const int Mi = in_sizes[0] / Ki;

  const size_t nx = (size_t)Mi * Ki;
  const size_t nw = (size_t)Ni * Ki;

  if (ws_size >= (nx + nw) * sizeof(uint16_t) && (Ki % 32) == 0 &&
      (Mi % 128) == 0 && (Ni % 128) == 0) {
    uint16_t* xb = (uint16_t*)d_ws;
    uint16_t* wb = xb + nx;
    cvt_f32_to_bf16<<<(int)(nx / 2048), 256, 0, stream>>>(x, (uint4*)xb);
    cvt_f32_to_bf16<<<(int)(nw / 2048), 256, 0, stream>>>(w, (uint4*)wb);

    if ((Mi % 256) == 0 && (Ni % 256) == 0 && (Ki % 128) == 0 && Ki >= 256) {
      dim3 grid((Mi / 256) * (Ni / 256));
      gemm256_8phase<<<grid, 512, 0, stream>>>(xb, wb, bias, out, Mi, Ni, Ki);
    } else {
      dim3 grid((Mi / 128) * (Ni / 128));
      gemm_bf16_bias<<<grid, 256, 0, stream>>>(xb, wb, bias, out, Mi, Ni, Ki);
    }
  } else {
    long total = (long)Mi * Ni;
    naive_gemm<<<(int)((total + 255) / 256), 256, 0, stream>>>(x, w, bias, out,
                                                               Mi, Ni, Ki);
  }
}

// Round 15
// 322.271 us; speedup vs baseline: 1.1279x; 1.0508x over previous
//
#include <hip/hip_runtime.h>
#include <hip/hip_bf16.h>
#include <stdint.h>

typedef __bf16 bf16x8 __attribute__((ext_vector_type(8)));
typedef float  f32x4  __attribute__((ext_vector_type(4)));
typedef float  f32x16 __attribute__((ext_vector_type(16)));

static constexpr float kScale = 0.0078125f;  // 1/128

// ---------- f32 -> bf16 (RNE) convert, 8 elems/thread, FUSED x+w ----------
static __device__ __forceinline__ uint32_t bf16_rne(float f) {
  uint32_t u = __builtin_bit_cast(uint32_t, f);
  u += 0x7FFFu + ((u >> 16) & 1u);
  return u >> 16;
}
static __device__ __forceinline__ uint32_t pack2(float lo, float hi) {
  return bf16_rne(lo) | (bf16_rne(hi) << 16);
}

// One launch converts x (nx elems) then w (nw elems) into the contiguous
// workspace (wb = xb + nx).  nx % 2048 == 0 -> no block straddles the seam.
__global__ __launch_bounds__(256) void cvt_fused(
    const float* __restrict__ x, const float* __restrict__ w,
    uint4* __restrict__ dst, long nx8 /* nx/8 */) {
  const long i = (long)blockIdx.x * 256 + threadIdx.x;
  const float4* sv;
  long j;
  if (i < nx8) { sv = reinterpret_cast<const float4*>(x); j = i; }
  else         { sv = reinterpret_cast<const float4*>(w); j = i - nx8; }
  float4 a = sv[2 * j];
  float4 b = sv[2 * j + 1];
  uint4 o;
  o.x = pack2(a.x, a.y);
  o.y = pack2(a.z, a.w);
  o.z = pack2(b.x, b.y);
  o.w = pack2(b.z, b.w);
  dst[i] = o;
}

__global__ __launch_bounds__(256) void cvt_f32_to_bf16(
    const float* __restrict__ src, uint4* __restrict__ dst) {
  const int i = blockIdx.x * 256 + threadIdx.x;
  const float4* sv = reinterpret_cast<const float4*>(src);
  float4 a = sv[2 * i];
  float4 b = sv[2 * i + 1];
  uint4 o;
  o.x = pack2(a.x, a.y);
  o.y = pack2(a.z, a.w);
  o.z = pack2(b.x, b.y);
  o.w = pack2(b.z, b.w);
  dst[i] = o;
}

// ---------- async global->LDS, 16B per lane ----------
static __device__ __forceinline__ void gload_lds16(const void* g, void* l) {
  __builtin_amdgcn_global_load_lds(
      (const __attribute__((address_space(1))) void*)g,
      (__attribute__((address_space(3))) void*)l, 16, 0, 0);
}

#define BARRIER() __builtin_amdgcn_s_barrier()
#define VMW(n) asm volatile("s_waitcnt vmcnt(" #n ")" ::: "memory")

// =====================================================================
// GEMM = R12 verified best (291us, 944 TF, 0 bank conflicts):
// 256x256 tile, BK=64, 8 waves 2Mx4N, mfma_32x32x16, one barrier per
// phase AFTER the MFMA cluster, vmcnt(6) only at P4/P8, 8bm x 4bn
// super-tile L2 dedup, stride-8-aware LDS swizzle (both-sides
// involution): granule = kb ^ ((kb&1)<<2) ^ (row&7) ^ ((row>>3)&3).
// =====================================================================
constexpr int TILE_V = (256 * 64) / 8;  // bf16x8 vectors per buffer

template <int MH, int NH>
__device__ __forceinline__ void quad32(f32x16 (&acc)[4][2],
                                       const bf16x8 (&aF)[2][4],
                                       const bf16x8 (&bF)[4]) {
  __builtin_amdgcn_s_setprio(1);
#pragma unroll
  for (int ks = 0; ks < 4; ++ks)
#pragma unroll
    for (int mt = 0; mt < 2; ++mt)
      acc[MH * 2 + mt][NH] = __builtin_amdgcn_mfma_f32_32x32x16_bf16(
          aF[mt][ks], bF[ks], acc[MH * 2 + mt][NH], 0, 0, 0);
  __builtin_amdgcn_s_setprio(0);
}

// vec col for k-slot ks: (ks<<1) ^ erk, erk = l7 ^ ((l31>>3)&3) ^ lk ^ (lk<<2)
template <int BUF, int MH>
__device__ __forceinline__ void loadA32(bf16x8 (&aF)[2][4], const bf16x8* Av,
                                        int wr, int l31, int erk) {
#pragma unroll
  for (int ks = 0; ks < 4; ++ks)
#pragma unroll
    for (int mt = 0; mt < 2; ++mt) {
      const int row = (MH << 7) + (wr << 6) + (mt << 5) + l31;
      aF[mt][ks] = Av[BUF * TILE_V + row * 8 + ((ks << 1) ^ erk)];
    }
}
template <int BUF, int NH>
__device__ __forceinline__ void loadB32(bf16x8 (&bF)[4], const bf16x8* Bv,
                                        int wc, int l31, int erk) {
  const int row = (NH << 7) + (wc << 5) + l31;
#pragma unroll
  for (int ks = 0; ks < 4; ++ks)
    bF[ks] = Bv[BUF * TILE_V + row * 8 + ((ks << 1) ^ erk)];
}

__global__ __launch_bounds__(512, 2) void gemm256_8phase(
    const uint16_t* __restrict__ A, const uint16_t* __restrict__ B,
    const float* __restrict__ bias, float* __restrict__ C,
    int Mi, int Ni, int Ki) {
  __shared__ __align__(16) uint16_t As[2][256 * 64];  // 64 KB
  __shared__ __align__(16) uint16_t Bs[2][256 * 64];  // 64 KB

  const int tid = threadIdx.x;
  const int l   = tid & 63;
  const int wv  = tid >> 6;
  const int wr  = wv >> 2;   // 0..1
  const int wc  = wv & 3;    // 0..3
  const int l31 = l & 31;
  const int lk  = l >> 5;
  const int l8  = l >> 3;
  const int l7  = l & 7;

  // read-side granule key
  const int erk = l7 ^ ((l31 >> 3) & 3) ^ lk ^ (lk << 2);

  const int nbm = Mi >> 8, nbn = Ni >> 8;
  const int nwg = nbm * nbn;
  const int q = nwg >> 3, r = nwg & 7;
  const int xcd = (int)blockIdx.x & 7, orig = (int)blockIdx.x >> 3;
  const int swz = (xcd < r ? xcd * (q + 1) : r * (q + 1) + (xcd - r) * q) + orig;

  // 8bm x 4bn super-tile mapping (L2 dedup across concurrent CUs)
  int bm, bn;
  if ((nbm & 7) == 0 && (nbn & 3) == 0) {
    const int s = swz >> 5;
    const int o = swz & 31;
    const int nsc = nbn >> 2;
    bm = (s / nsc) * 8 + (o >> 2);
    bn = (s % nsc) * 4 + (o & 3);
  } else {
    bm = swz / nbn;
    bn = swz % nbn;
  }

  // staging: wave wv covers rows chunk+wv*8+l8; global source col encodes
  // the inverse involution: u = l7^l8^(wv&3); kb = u ^ ((u&1)<<2).
  const int u0   = l7 ^ l8 ^ (wv & 3);
  const int xcol = (u0 ^ ((u0 & 1) << 2)) << 3;
  const uint16_t* gA0 = A + (size_t)((bm << 8) + (wv << 3) + l8) * Ki + xcol;
  const uint16_t* gB0 = B + (size_t)((bn << 8) + (wv << 3) + l8) * Ki + xcol;

#define STAGE_A(bufi, chunk, t)                        \
  gload_lds16(gA0 + (size_t)(chunk) * Ki + (t) * 64,   \
              &As[bufi][((chunk) + (wv << 3)) << 6])
#define STAGE_B(bufi, chunk, t)                        \
  gload_lds16(gB0 + (size_t)(chunk) * Ki + (t) * 64,   \
              &Bs[bufi][((chunk) + (wv << 3)) << 6])

  const bf16x8* Av = reinterpret_cast<const bf16x8*>(&As[0][0]);
  const bf16x8* Bv = reinterpret_cast<const bf16x8*>(&Bs[0][0]);

  f32x16 acc[4][2] = {};
  bf16x8 aF[2][4], b0[4], b1[4];

  const int NT = Ki >> 6;   // K-tiles (Ki % 128 == 0, Ki >= 256)
  const int NI = NT >> 1;

  // ---- prologue: t0 all 4 halves + t1 {Ah0,Bh0,Bh1} ----
  STAGE_A(0, 0, 0);   STAGE_A(0, 64, 0);    // t0 A-h0
  STAGE_B(0, 0, 0);   STAGE_B(0, 64, 0);    // t0 B-h0
  STAGE_B(0, 128, 0); STAGE_B(0, 192, 0);   // t0 B-h1
  STAGE_A(0, 128, 0); STAGE_A(0, 192, 0);   // t0 A-h1
  STAGE_A(1, 0, 1);   STAGE_A(1, 64, 1);    // t1 A-h0
  STAGE_B(1, 0, 1);   STAGE_B(1, 64, 1);    // t1 B-h0
  STAGE_B(1, 128, 1); STAGE_B(1, 192, 1);   // t1 B-h1
  VMW(6);
  BARRIER();

#pragma unroll 1
  for (int i = 0; i < NI - 1; ++i) {
    const int t1 = 2 * i + 1, t2 = 2 * i + 2, t3 = 2 * i + 3;

    // P1: reads buf0 {Bh0, Ah0} ; stage t1 A-h1 ; Q(0,0) ; BAR
    loadB32<0, 0>(b0, Bv, wc, l31, erk);
    loadA32<0, 0>(aF, Av, wr, l31, erk);
    STAGE_A(1, 128, t1); STAGE_A(1, 192, t1);
    quad32<0, 0>(acc, aF, b0);
    BARRIER();

    // P2: reads buf0 Bh1 ; stage t2 A-h0 ; Q(0,1) ; BAR
    loadB32<0, 1>(b1, Bv, wc, l31, erk);
    STAGE_A(0, 0, t2); STAGE_A(0, 64, t2);
    quad32<0, 1>(acc, aF, b1);
    BARRIER();

    // P3: reads buf0 Ah1 ; stage t2 B-h0 ; Q(1,0) ; BAR
    loadA32<0, 1>(aF, Av, wr, l31, erk);
    STAGE_B(0, 0, t2); STAGE_B(0, 64, t2);
    quad32<1, 0>(acc, aF, b0);
    BARRIER();

    // P4: stage t2 B-h1 ; Q(1,1) ; VMW(6) forces all of t1 ; BAR
    STAGE_B(0, 128, t2); STAGE_B(0, 192, t2);
    quad32<1, 1>(acc, aF, b1);
    VMW(6);
    BARRIER();

    // P5: reads buf1 {Bh0, Ah0} ; stage t2 A-h1 ; Q(0,0) ; BAR
    loadB32<1, 0>(b0, Bv, wc, l31, erk);
    loadA32<1, 0>(aF, Av, wr, l31, erk);
    STAGE_A(0, 128, t2); STAGE_A(0, 192, t2);
    quad32<0, 0>(acc, aF, b0);
    BARRIER();

    // P6: reads buf1 Bh1 ; stage t3 A-h0 ; Q(0,1) ; BAR
    loadB32<1, 1>(b1, Bv, wc, l31, erk);
    STAGE_A(1, 0, t3); STAGE_A(1, 64, t3);
    quad32<0, 1>(acc, aF, b1);
    BARRIER();

    // P7: reads buf1 Ah1 ; stage t3 B-h0 ; Q(1,0) ; BAR
    loadA32<1, 1>(aF, Av, wr, l31, erk);
    STAGE_B(1, 0, t3); STAGE_B(1, 64, t3);
    quad32<1, 0>(acc, aF, b0);
    BARRIER();

    // P8: stage t3 B-h1 ; Q(1,1) ; VMW(6) forces all of t2 ; BAR
    STAGE_B(1, 128, t3); STAGE_B(1, 192, t3);
    quad32<1, 1>(acc, aF, b1);
    VMW(6);
    BARRIER();
  }

  // ---- peeled last iteration (tiles NT-2 buf0, NT-1 buf1) ----
  {
    const int t1 = NT - 1;
    // P1
    loadB32<0, 0>(b0, Bv, wc, l31, erk);
    loadA32<0, 0>(aF, Av, wr, l31, erk);
    STAGE_A(1, 128, t1); STAGE_A(1, 192, t1);
    quad32<0, 0>(acc, aF, b0);
    BARRIER();
    // P2
    loadB32<0, 1>(b1, Bv, wc, l31, erk);
    quad32<0, 1>(acc, aF, b1);
    BARRIER();
    // P3
    loadA32<0, 1>(aF, Av, wr, l31, erk);
    quad32<1, 0>(acc, aF, b0);
    BARRIER();
    // P4: drain everything so buf1 (t_{NT-1}) is complete
    quad32<1, 1>(acc, aF, b1);
    VMW(0);
    BARRIER();
    // P5
    loadB32<1, 0>(b0, Bv, wc, l31, erk);
    loadA32<1, 0>(aF, Av, wr, l31, erk);
    quad32<0, 0>(acc, aF, b0);
    BARRIER();
    // P6
    loadB32<1, 1>(b1, Bv, wc, l31, erk);
    quad32<0, 1>(acc, aF, b1);
    BARRIER();
    // P7
    loadA32<1, 1>(aF, Av, wr, l31, erk);
    quad32<1, 0>(acc, aF, b0);
    BARRIER();
    // P8 (register-only)
    quad32<1, 1>(acc, aF, b1);
  }

  // ---- epilogue (32x32 C/D layout, m74/m101): col = lane&31,
  // row = (reg&3) + 8*(reg>>2) + 4*lk within each 32x32 tile.
  const int rowB = (bm << 8) + (wr << 6) + 4 * lk;
  const int colB = (bn << 8) + (wc << 5) + l31;
#pragma unroll
  for (int mt4 = 0; mt4 < 4; ++mt4) {
    const int rBase = rowB + (mt4 >> 1) * 128 + (mt4 & 1) * 32;
#pragma unroll
    for (int nh = 0; nh < 2; ++nh) {
      const int col = colB + nh * 128;
      const float bv = bias[col];
#pragma unroll
      for (int reg = 0; reg < 16; ++reg) {
        const int row = rBase + (reg & 3) + 8 * (reg >> 2);
        C[(size_t)row * Ni + col] = acc[mt4][nh][reg] * kScale + bv;
      }
    }
  }
}

// =====================================================================
// proven 128x128 fallback for non-conforming shapes
// =====================================================================
__global__ __launch_bounds__(256) void gemm_bf16_bias(
    const uint16_t* __restrict__ A, const uint16_t* __restrict__ B,
    const float* __restrict__ bias, float* __restrict__ C,
    int Mi, int Ni, int Ki) {
  __shared__ __align__(16) uint16_t As[128 * 32];
  __shared__ __align__(16) uint16_t Bs[128 * 32];

  const int tid  = threadIdx.x;
  const int lane = tid & 63;
  const int wv   = tid >> 6;
  const int wr   = wv >> 1;
  const int wc   = wv & 1;
  const int fr   = lane & 15;
  const int fh   = lane >> 4;

  const int nTilesN = Ni >> 7;
  const int nwg = gridDim.x;
  const int q = nwg >> 3, r = nwg & 7;
  const int xcd = (int)blockIdx.x & 7, orig = (int)blockIdx.x >> 3;
  const int swz = (xcd < r ? xcd * (q + 1) : r * (q + 1) + (xcd - r) * q) + orig;
  const int bm = swz / nTilesN;
  const int bn = swz % nTilesN;

  const int sRow = tid >> 2;
  const int sCol = (tid & 3) << 3;

  const uint16_t* gA0 = A + (size_t)(bm * 128 + sRow) * Ki + sCol;
  const uint16_t* gA1 = gA0 + (size_t)64 * Ki;
  const uint16_t* gB0 = B + (size_t)(bn * 128 + sRow) * Ki + sCol;
  const uint16_t* gB1 = gB0 + (size_t)64 * Ki;
  uint16_t* lA0 = &As[tid * 8];
  uint16_t* lA1 = &As[(256 + tid) * 8];
  uint16_t* lB0 = &Bs[tid * 8];
  uint16_t* lB1 = &Bs[(256 + tid) * 8];

  const bf16x8* Av = reinterpret_cast<const bf16x8*>(As);
  const bf16x8* Bv = reinterpret_cast<const bf16x8*>(Bs);

  f32x4 acc[4][4] = {};

  for (int k0 = 0; k0 < Ki; k0 += 32) {
    gload_lds16(gA0 + k0, lA0);
    gload_lds16(gA1 + k0, lA1);
    gload_lds16(gB0 + k0, lB0);
    gload_lds16(gB1 + k0, lB1);
    __syncthreads();

    bf16x8 af[4], bfr[4];
#pragma unroll
    for (int m = 0; m < 4; ++m) af[m] = Av[(wr * 64 + m * 16 + fr) * 4 + fh];
#pragma unroll
    for (int n = 0; n < 4; ++n) bfr[n] = Bv[(wc * 64 + n * 16 + fr) * 4 + fh];

#pragma unroll
    for (int m = 0; m < 4; ++m)
#pragma unroll
      for (int n = 0; n < 4; ++n)
        acc[m][n] = __builtin_amdgcn_mfma_f32_16x16x32_bf16(af[m], bfr[n],
                                                            acc[m][n], 0, 0, 0);
    __syncthreads();
  }

  const int rowBase = bm * 128 + wr * 64;
  const int colBase = bn * 128 + wc * 64;
#pragma unroll
  for (int n = 0; n < 4; ++n) {
    const int col = colBase + n * 16 + fr;
    const float bv = bias[col];
#pragma unroll
    for (int m = 0; m < 4; ++m) {
      const int row = rowBase + m * 16 + fh * 4;
#pragma unroll
      for (int j = 0; j < 4; ++j)
        C[(size_t)(row + j) * Ni + col] = acc[m][n][j] * kScale + bv;
    }
  }
}

// ---------- fallback: naive f32 ----------
__global__ void naive_gemm(const float* __restrict__ x, const float* __restrict__ w,
                           const float* __restrict__ bias, float* __restrict__ out,
                           int Mi, int Ni, int Ki) {
  long idx = (long)blockIdx.x * blockDim.x + threadIdx.x;
  if (idx >= (long)Mi * Ni) return;
  int m = (int)(idx / Ni), n = (int)(idx % Ni);
  float s = 0.f;
  for (int k = 0; k < Ki; ++k) s += x[(long)m * Ki + k] * w[(long)n * Ki + k];
  out[idx] = s * kScale + bias[n];
}

extern "C" void kernel_launch(void* const* d_in, const int* in_sizes, int n_in,
                              void* d_out, int out_size, void* d_ws, size_t ws_size,
                              hipStream_t stream) {
  const float* x    = (const float*)d_in[0];
  const float* w    = (const float*)d_in[1];
  const float* bias = (const float*)d_in[2];
  float* out = (float*)d_out;

  const int Ni = in_sizes[2];
  const int Ki = in_sizes[1] / Ni;
  const int Mi = in_sizes[0] / Ki;

  const size_t nx = (size_t)Mi * Ki;
  const size_t nw = (size_t)Ni * Ki;

  if (ws_size >= (nx + nw) * sizeof(uint16_t) && (Ki % 32) == 0 &&
      (Mi % 128) == 0 && (Ni % 128) == 0) {
    uint16_t* xb = (uint16_t*)d_ws;
    uint16_t* wb = xb + nx;

    if ((nx % 2048) == 0 && (nw % 2048) == 0) {
      // fused convert: one launch for both tensors (dst contiguous)
      long total8 = (long)((nx + nw) / 8);
      cvt_fused<<<(int)(total8 / 256), 256, 0, stream>>>(x, w, (uint4*)xb,
                                                         (long)(nx / 8));
    } else {
      cvt_f32_to_bf16<<<(int)(nx / 2048), 256, 0, stream>>>(x, (uint4*)xb);
      cvt_f32_to_bf16<<<(int)(nw / 2048), 256, 0, stream>>>(w, (uint4*)wb);
    }

    if ((Mi % 256) == 0 && (Ni % 256) == 0 && (Ki % 128) == 0 && Ki >= 256) {
      dim3 grid((Mi / 256) * (Ni / 256));
      gemm256_8phase<<<grid, 512, 0, stream>>>(xb, wb, bias, out, Mi, Ni, Ki);
    } else {
      dim3 grid((Mi / 128) * (Ni / 128));
      gemm_bf16_bias<<<grid, 256, 0, stream>>>(xb, wb, bias, out, Mi, Ni, Ki);
    }
  } else {
    long total = (long)Mi * Ni;
    naive_gemm<<<(int)((total + 255) / 256), 256, 0, stream>>>(x, w, bias, out,
                                                               Mi, Ni, Ki);
  }
}